// Round 1
// baseline (4435.450 us; speedup 1.0000x reference)
//
#include <hip/hip_runtime.h>

#define BLK 256

__device__ __forceinline__ void fadd_atomic(float* p, float v) {
    unsafeAtomicAdd(p, v);  // HW global_atomic_add_f32 on gfx950
}

// deg[i] = 1.0 (self-loop contribution)
__global__ void k_init_deg(float* __restrict__ deg, int N) {
    int i = blockIdx.x * BLK + threadIdx.x;
    if (i < N) deg[i] = 1.0f;
}

// deg[dst] += 1 per edge
__global__ void k_deg_count(const int* __restrict__ dst, float* __restrict__ deg,
                            int E, int E4) {
    int t = blockIdx.x * BLK + threadIdx.x;
    int stride = gridDim.x * BLK;
    const int4* d4 = (const int4*)dst;
    for (int i = t; i < E4; i += stride) {
        int4 d = d4[i];
        fadd_atomic(&deg[d.x], 1.0f);
        fadd_atomic(&deg[d.y], 1.0f);
        fadd_atomic(&deg[d.z], 1.0f);
        fadd_atomic(&deg[d.w], 1.0f);
    }
    for (int i = (E4 << 2) + t; i < E; i += stride)
        fadd_atomic(&deg[dst[i]], 1.0f);
}

// dinv = rsqrt(deg); p = dinv*(x@W1); agg = dinv*p  (self-loop term)
__global__ void k_node_first(const float* __restrict__ x, const float* __restrict__ deg,
                             const float* __restrict__ W,
                             float* __restrict__ dinv, float2* __restrict__ p,
                             float2* __restrict__ agg, int N) {
    int i = blockIdx.x * BLK + threadIdx.x;
    if (i >= N) return;
    float w00 = W[0], w01 = W[1], w10 = W[2], w11 = W[3];
    float di = rsqrtf(deg[i]);
    dinv[i] = di;
    float2 xv = ((const float2*)x)[i];
    float p0 = di * (xv.x * w00 + xv.y * w10);
    float p1 = di * (xv.x * w01 + xv.y * w11);
    p[i] = make_float2(p0, p1);
    agg[i] = make_float2(di * p0, di * p1);
}

// agg[dst] += p[src]  (normalization factored: agg later scaled by dinv[dst])
__global__ void k_edge_agg(const int* __restrict__ src, const int* __restrict__ dst,
                           const float2* __restrict__ p, float* __restrict__ agg,
                           int E, int E4) {
    int t = blockIdx.x * BLK + threadIdx.x;
    int stride = gridDim.x * BLK;
    const int4* s4 = (const int4*)src;
    const int4* d4 = (const int4*)dst;
    for (int i = t; i < E4; i += stride) {
        int4 s = s4[i];
        int4 d = d4[i];
        float2 h;
        h = p[s.x]; fadd_atomic(&agg[2 * d.x], h.x); fadd_atomic(&agg[2 * d.x + 1], h.y);
        h = p[s.y]; fadd_atomic(&agg[2 * d.y], h.x); fadd_atomic(&agg[2 * d.y + 1], h.y);
        h = p[s.z]; fadd_atomic(&agg[2 * d.z], h.x); fadd_atomic(&agg[2 * d.z + 1], h.y);
        h = p[s.w]; fadd_atomic(&agg[2 * d.w], h.x); fadd_atomic(&agg[2 * d.w + 1], h.y);
    }
    for (int i = (E4 << 2) + t; i < E; i += stride) {
        int s = src[i], d = dst[i];
        float2 h = p[s];
        fadd_atomic(&agg[2 * d], h.x);
        fadd_atomic(&agg[2 * d + 1], h.y);
    }
}

// h = relu(dinv*agg + b); p = dinv*(h@W); agg = dinv*p   (in-place on agg)
__global__ void k_node_mid(const float* __restrict__ b, const float* __restrict__ W,
                           const float* __restrict__ dinv,
                           float2* __restrict__ p, float2* __restrict__ agg, int N) {
    int i = blockIdx.x * BLK + threadIdx.x;
    if (i >= N) return;
    float b0 = b[0], b1 = b[1];
    float w00 = W[0], w01 = W[1], w10 = W[2], w11 = W[3];
    float di = dinv[i];
    float2 a = agg[i];
    float h0 = fmaxf(fmaf(di, a.x, b0), 0.0f);
    float h1 = fmaxf(fmaf(di, a.y, b1), 0.0f);
    float p0 = di * (h0 * w00 + h1 * w10);
    float p1 = di * (h0 * w01 + h1 * w11);
    p[i] = make_float2(p0, p1);
    agg[i] = make_float2(di * p0, di * p1);
}

__global__ void k_out_init(float* __restrict__ out, const float* __restrict__ br, int G) {
    int i = blockIdx.x * BLK + threadIdx.x;
    if (i < G) out[i] = br[0];
}

// h = relu(dinv*agg + b3); s = h@Wr; wave-segmented reduce on sorted batch; atomic per segment
__global__ void k_node_final(const float* __restrict__ b, const float* __restrict__ Wr,
                             const float* __restrict__ dinv, const float2* __restrict__ agg,
                             const int* __restrict__ batch, float* __restrict__ out, int N) {
    int i = blockIdx.x * BLK + threadIdx.x;
    bool valid = i < N;
    float b0 = b[0], b1 = b[1], wr0 = Wr[0], wr1 = Wr[1];
    float s = 0.0f;
    int k = -1;
    if (valid) {
        float di = dinv[i];
        float2 a = agg[i];
        float h0 = fmaxf(fmaf(di, a.x, b0), 0.0f);
        float h1 = fmaxf(fmaf(di, a.y, b1), 0.0f);
        s = fmaf(h0, wr0, h1 * wr1);
        k = batch[i];
    }
    int lane = threadIdx.x & 63;
    // segmented suffix-sum over sorted keys within the wave
    for (int off = 1; off < 64; off <<= 1) {
        float s2 = __shfl_down(s, off);
        int k2 = __shfl_down(k, off);
        if (lane + off < 64 && k2 == k) s += s2;
    }
    int kprev = __shfl_up(k, 1);
    if (valid && (lane == 0 || kprev != k)) fadd_atomic(&out[k], s);
}

extern "C" void kernel_launch(void* const* d_in, const int* in_sizes, int n_in,
                              void* d_out, int out_size, void* d_ws, size_t ws_size,
                              hipStream_t stream) {
    const float* x   = (const float*)d_in[0];
    const int*  ei   = (const int*)d_in[1];
    const int*  batch= (const int*)d_in[2];
    const float* W1  = (const float*)d_in[3];
    const float* b1  = (const float*)d_in[4];
    const float* W2  = (const float*)d_in[5];
    const float* b2  = (const float*)d_in[6];
    const float* W3  = (const float*)d_in[7];
    const float* b3  = (const float*)d_in[8];
    const float* Wr  = (const float*)d_in[9];
    const float* br  = (const float*)d_in[10];
    float* out = (float*)d_out;

    int N = in_sizes[0] / 2;   // x is [N,2]
    int E = in_sizes[1] / 2;   // edge_index is [2,E]
    int G = out_size;
    const int* src = ei;
    const int* dst = ei + E;

    // workspace carve: deg[N], dinv[N], p[2N], agg[2N]  (6N floats)
    float* ws   = (float*)d_ws;
    float* deg  = ws;
    float* dinv = ws + N;
    float2* p   = (float2*)(ws + 2 * (size_t)N);
    float2* agg = (float2*)(ws + 4 * (size_t)N);

    int NB = (N + BLK - 1) / BLK;
    // int4 vector path only valid when dst = ei+E stays 16B-aligned
    int E4 = ((E & 3) == 0) ? (E >> 2) : 0;
    int items = (E4 > 0) ? E4 : E;
    int EB = (items + BLK - 1) / BLK;
    if (EB < 1) EB = 1;
    int GB = (G + BLK - 1) / BLK;

    k_init_deg<<<NB, BLK, 0, stream>>>(deg, N);
    k_deg_count<<<EB, BLK, 0, stream>>>(dst, deg, E, E4);

    k_node_first<<<NB, BLK, 0, stream>>>(x, deg, W1, dinv, p, agg, N);
    k_edge_agg<<<EB, BLK, 0, stream>>>(src, dst, p, (float*)agg, E, E4);

    k_node_mid<<<NB, BLK, 0, stream>>>(b1, W2, dinv, p, agg, N);
    k_edge_agg<<<EB, BLK, 0, stream>>>(src, dst, p, (float*)agg, E, E4);

    k_node_mid<<<NB, BLK, 0, stream>>>(b2, W3, dinv, p, agg, N);
    k_edge_agg<<<EB, BLK, 0, stream>>>(src, dst, p, (float*)agg, E, E4);

    k_out_init<<<GB, BLK, 0, stream>>>(out, br, G);
    k_node_final<<<NB, BLK, 0, stream>>>(b3, Wr, dinv, agg, batch, out, N);
}

// Round 2
// 890.167 us; speedup vs baseline: 4.9827x; 4.9827x over previous
//
#include <hip/hip_runtime.h>

#define BLK 256
#define BSHIFT 8            // 256 nodes per bucket
#define BSIZE  256
#define NSLICE 512          // edge slices for hist/scatter

// ---------------- CSR-ish bucketed build (no global atomics) ----------------

// per-slice histogram of dst buckets -> partial[s][K]
__global__ void k_hist(const int* __restrict__ dst, int* __restrict__ partial,
                       int E, int chunk, int K) {
    extern __shared__ int cnt[];           // K ints
    int s = blockIdx.x;
    for (int i = threadIdx.x; i < K; i += BLK) cnt[i] = 0;
    __syncthreads();
    int lo = s * chunk, hi = min(E, lo + chunk);
    for (int i = lo + threadIdx.x; i < hi; i += BLK)
        atomicAdd(&cnt[dst[i] >> BSHIFT], 1);
    __syncthreads();
    int* prow = partial + (size_t)s * K;
    for (int i = threadIdx.x; i < K; i += BLK) prow[i] = cnt[i];
}

// totals[k] = sum_s partial[s][k]
__global__ void k_totals(const int* __restrict__ partial, int* __restrict__ totals,
                         int S, int K) {
    int k = blockIdx.x * BLK + threadIdx.x;
    if (k >= K) return;
    int t = 0;
    for (int s = 0; s < S; ++s) t += partial[(size_t)s * K + k];
    totals[k] = t;
}

// exclusive scan of totals -> base[0..K]  (single block; requires K <= 1024)
__global__ void k_base(const int* __restrict__ totals, int* __restrict__ base, int K) {
    __shared__ int sh[1024];
    int t = threadIdx.x;
    sh[t] = (t < K) ? totals[t] : 0;
    __syncthreads();
    for (int off = 1; off < 1024; off <<= 1) {
        int u = (t >= off) ? sh[t - off] : 0;
        __syncthreads();
        sh[t] += u;
        __syncthreads();
    }
    if (t < K) base[t + 1] = sh[t];
    if (t == 0) base[0] = 0;
}

// in-place: partial[s][k] becomes write offset for (slice s, bucket k)
__global__ void k_offsets(int* __restrict__ partial, const int* __restrict__ base,
                          int S, int K) {
    int k = blockIdx.x * BLK + threadIdx.x;
    if (k >= K) return;
    int run = base[k];
    for (int s = 0; s < S; ++s) {
        size_t idx = (size_t)s * K + k;
        int t = partial[idx];
        partial[idx] = run;
        run += t;
    }
}

// scatter edges into bucketed array: packed = (dst_local<<24) | src   (src < 2^24)
__global__ void k_scatter(const int* __restrict__ src, const int* __restrict__ dst,
                          const int* __restrict__ offs, int* __restrict__ packed,
                          int E, int chunk, int K) {
    extern __shared__ int cur[];           // K ints
    int s = blockIdx.x;
    const int* orow = offs + (size_t)s * K;
    for (int i = threadIdx.x; i < K; i += BLK) cur[i] = orow[i];
    __syncthreads();
    int lo = s * chunk, hi = min(E, lo + chunk);
    for (int i = lo + threadIdx.x; i < hi; i += BLK) {
        int d = dst[i];
        int k = d >> BSHIFT;
        int pos = atomicAdd(&cur[k], 1);
        packed[pos] = ((d & (BSIZE - 1)) << 24) | src[i];
    }
}

// ---------------- fused GCN passes (block = bucket, LDS accumulate) ---------

// deg from bucketed edges (+1 self loop) -> dinv; fused p1 = dinv*(x@W1)
__global__ void k_deg_node1(const int* __restrict__ packed, const int* __restrict__ base,
                            const float* __restrict__ x, const float* __restrict__ W1,
                            float* __restrict__ dinv, float2* __restrict__ p1, int N) {
    __shared__ int cnt[BSIZE];
    int k = blockIdx.x;
    cnt[threadIdx.x] = 0;
    __syncthreads();
    int lo = base[k], hi = base[k + 1];
    for (int i = lo + threadIdx.x; i < hi; i += BLK)
        atomicAdd(&cnt[((unsigned)packed[i]) >> 24], 1);
    __syncthreads();
    int node = (k << BSHIFT) + threadIdx.x;
    if (node < N) {
        float di = rsqrtf((float)cnt[threadIdx.x] + 1.0f);
        dinv[node] = di;
        float2 xv = ((const float2*)x)[node];
        float w00 = W1[0], w01 = W1[1], w10 = W1[2], w11 = W1[3];
        p1[node] = make_float2(di * (xv.x * w00 + xv.y * w10),
                               di * (xv.x * w01 + xv.y * w11));
    }
}

// mid layer: agg (LDS) -> h=relu(dinv*agg+b) -> pout = dinv*(h@W)
__global__ void k_layer_mid(const int* __restrict__ packed, const int* __restrict__ base,
                            const float* __restrict__ dinv, const float2* __restrict__ pin,
                            const float* __restrict__ b, const float* __restrict__ W,
                            float2* __restrict__ pout, int N) {
    __shared__ float accx[BSIZE], accy[BSIZE];
    int k = blockIdx.x;
    int node = (k << BSHIFT) + threadIdx.x;
    float2 self = (node < N) ? pin[node] : make_float2(0.f, 0.f);
    accx[threadIdx.x] = self.x;
    accy[threadIdx.x] = self.y;
    __syncthreads();
    int lo = base[k], hi = base[k + 1];
    for (int i = lo + threadIdx.x; i < hi; i += BLK) {
        unsigned v = (unsigned)packed[i];
        int l = v >> 24;
        int s = v & 0xFFFFFF;
        float2 pv = pin[s];
        atomicAdd(&accx[l], pv.x);
        atomicAdd(&accy[l], pv.y);
    }
    __syncthreads();
    if (node < N) {
        float di = dinv[node];
        float b0 = b[0], b1 = b[1];
        float w00 = W[0], w01 = W[1], w10 = W[2], w11 = W[3];
        float h0 = fmaxf(fmaf(di, accx[threadIdx.x], b0), 0.f);
        float h1 = fmaxf(fmaf(di, accy[threadIdx.x], b1), 0.f);
        pout[node] = make_float2(di * (h0 * w00 + h1 * w10),
                                 di * (h0 * w01 + h1 * w11));
    }
}

// final layer: agg -> h=relu(dinv*agg+b3) -> s = h@Wr  (scalar per node)
__global__ void k_layer_final(const int* __restrict__ packed, const int* __restrict__ base,
                              const float* __restrict__ dinv, const float2* __restrict__ pin,
                              const float* __restrict__ b, const float* __restrict__ Wr,
                              float* __restrict__ sv, int N) {
    __shared__ float accx[BSIZE], accy[BSIZE];
    int k = blockIdx.x;
    int node = (k << BSHIFT) + threadIdx.x;
    float2 self = (node < N) ? pin[node] : make_float2(0.f, 0.f);
    accx[threadIdx.x] = self.x;
    accy[threadIdx.x] = self.y;
    __syncthreads();
    int lo = base[k], hi = base[k + 1];
    for (int i = lo + threadIdx.x; i < hi; i += BLK) {
        unsigned v = (unsigned)packed[i];
        int l = v >> 24;
        int s = v & 0xFFFFFF;
        float2 pv = pin[s];
        atomicAdd(&accx[l], pv.x);
        atomicAdd(&accy[l], pv.y);
    }
    __syncthreads();
    if (node < N) {
        float di = dinv[node];
        float h0 = fmaxf(fmaf(di, accx[threadIdx.x], b[0]), 0.f);
        float h1 = fmaxf(fmaf(di, accy[threadIdx.x], b[1]), 0.f);
        sv[node] = fmaf(h0, Wr[0], h1 * Wr[1]);
    }
}

// ---------------- pooling ----------------

__global__ void k_out_init(float* __restrict__ out, const float* __restrict__ br, int G) {
    int i = blockIdx.x * BLK + threadIdx.x;
    if (i < G) out[i] = br[0];
}

__global__ void k_pool(const float* __restrict__ sv, const int* __restrict__ batch,
                       float* __restrict__ out, int N) {
    int i = blockIdx.x * BLK + threadIdx.x;
    bool valid = i < N;
    float s = valid ? sv[i] : 0.f;
    int k = valid ? batch[i] : -1;
    int lane = threadIdx.x & 63;
    for (int off = 1; off < 64; off <<= 1) {
        float s2 = __shfl_down(s, off);
        int k2 = __shfl_down(k, off);
        if (lane + off < 64 && k2 == k) s += s2;
    }
    int kprev = __shfl_up(k, 1);
    if (valid && (lane == 0 || kprev != k)) unsafeAtomicAdd(&out[k], s);
}

// ---------------- launch ----------------

extern "C" void kernel_launch(void* const* d_in, const int* in_sizes, int n_in,
                              void* d_out, int out_size, void* d_ws, size_t ws_size,
                              hipStream_t stream) {
    const float* x    = (const float*)d_in[0];
    const int*   ei   = (const int*)d_in[1];
    const int*   batch= (const int*)d_in[2];
    const float* W1   = (const float*)d_in[3];
    const float* b1   = (const float*)d_in[4];
    const float* W2   = (const float*)d_in[5];
    const float* b2   = (const float*)d_in[6];
    const float* W3   = (const float*)d_in[7];
    const float* b3   = (const float*)d_in[8];
    const float* Wr   = (const float*)d_in[9];
    const float* br   = (const float*)d_in[10];
    float* out = (float*)d_out;

    int N = in_sizes[0] / 2;
    int E = in_sizes[1] / 2;
    int G = out_size;
    const int* src = ei;
    const int* dst = ei + E;

    int K = (N + BSIZE - 1) >> BSHIFT;         // buckets (requires K <= 1024)
    int S = NSLICE;
    int chunk = (E + S - 1) / S;

    // workspace carve (16B aligned slots)
    char* w = (char*)d_ws;
    size_t off = 0;
    auto carve = [&](size_t bytes) { void* p = w + off; off += (bytes + 15) & ~(size_t)15; return p; };
    int*   packed  = (int*)carve((size_t)E * 4);
    int*   partial = (int*)carve((size_t)S * K * 4);
    int*   basep   = (int*)carve((size_t)(K + 1) * 4);
    int*   totals  = (int*)carve((size_t)K * 4);
    float* dinv    = (float*)carve((size_t)N * 4);
    float2* pA     = (float2*)carve((size_t)N * 8);
    float2* pB     = (float2*)carve((size_t)N * 8);
    float* sv      = (float*)carve((size_t)N * 4);
    if (off > ws_size) return;                  // fail loud (output stays poisoned)

    int KB = (K + BLK - 1) / BLK;
    int NB = (N + BLK - 1) / BLK;
    int GB = (G + BLK - 1) / BLK;
    size_t smemK = (size_t)K * 4;

    // build bucketed edge list
    k_hist   <<<S, BLK, smemK, stream>>>(dst, partial, E, chunk, K);
    k_totals <<<KB, BLK, 0, stream>>>(partial, totals, S, K);
    k_base   <<<1, 1024, 0, stream>>>(totals, basep, K);
    k_offsets<<<KB, BLK, 0, stream>>>(partial, basep, S, K);
    k_scatter<<<S, BLK, smemK, stream>>>(src, dst, partial, packed, E, chunk, K);

    // GCN layers
    k_deg_node1 <<<K, BLK, 0, stream>>>(packed, basep, x, W1, dinv, pA, N);
    k_layer_mid <<<K, BLK, 0, stream>>>(packed, basep, dinv, pA, b1, W2, pB, N);
    k_layer_mid <<<K, BLK, 0, stream>>>(packed, basep, dinv, pB, b2, W3, pA, N);
    k_layer_final<<<K, BLK, 0, stream>>>(packed, basep, dinv, pA, b3, Wr, sv, N);

    // pool + readout
    k_out_init<<<GB, BLK, 0, stream>>>(out, br, G);
    k_pool    <<<NB, BLK, 0, stream>>>(sv, batch, out, N);
}

// Round 3
// 737.895 us; speedup vs baseline: 6.0109x; 1.2064x over previous
//
#include <hip/hip_runtime.h>

#define BLK 256
#define BSHIFT 9
#define BSIZE 512            // nodes per bucket (local index: 9 bits)
#define NSLICE 512           // edge slices for hist/scatter
#define SCAN_T 512           // max K supported by single-block scan

// ---------------- bucketed edge build (no global atomics) ----------------

// per-slice histogram of dst buckets -> partial[s][K]
__global__ void k_hist(const int* __restrict__ dst, int* __restrict__ partial,
                       int E, int chunk, int K) {
    extern __shared__ int cnt[];
    int s = blockIdx.x;
    for (int i = threadIdx.x; i < K; i += BLK) cnt[i] = 0;
    __syncthreads();
    int lo = s * chunk, hi = min(E, lo + chunk);
    for (int i = lo + threadIdx.x; i < hi; i += BLK)
        atomicAdd(&cnt[((unsigned)dst[i]) >> BSHIFT], 1);
    __syncthreads();
    int* prow = partial + (size_t)s * K;
    for (int i = threadIdx.x; i < K; i += BLK) prow[i] = cnt[i];
}

__global__ void k_totals(const int* __restrict__ partial, int* __restrict__ totals,
                         int S, int K) {
    int k = blockIdx.x * BLK + threadIdx.x;
    if (k >= K) return;
    int t = 0;
    for (int s = 0; s < S; ++s) t += partial[(size_t)s * K + k];
    totals[k] = t;
}

// exclusive scan of totals -> base[0..K]  (K <= SCAN_T)
__global__ void k_base(const int* __restrict__ totals, int* __restrict__ base, int K) {
    __shared__ int sh[SCAN_T];
    int t = threadIdx.x;
    int v = (t < K) ? totals[t] : 0;
    sh[t] = v;
    __syncthreads();
    for (int off = 1; off < SCAN_T; off <<= 1) {
        int u = (t >= off) ? sh[t - off] : 0;
        __syncthreads();
        sh[t] += u;
        __syncthreads();
    }
    if (t < K) base[t + 1] = sh[t];
    if (t == 0) base[0] = 0;
}

// per-bucket column scan: partial[s][k] -> base[k] + exclusive_sum_s
__global__ void k_offsets(int* __restrict__ partial, const int* __restrict__ base, int K) {
    __shared__ int sh[NSLICE];
    int k = blockIdx.x;
    int t = threadIdx.x;                  // blockDim.x == NSLICE
    int v = partial[(size_t)t * K + k];
    sh[t] = v;
    __syncthreads();
    for (int off = 1; off < NSLICE; off <<= 1) {
        int u = (t >= off) ? sh[t - off] : 0;
        __syncthreads();
        sh[t] += u;
        __syncthreads();
    }
    partial[(size_t)t * K + k] = base[k] + sh[t] - v;
}

// scatter: packed = (dst_local << sbits) | src
__global__ void k_scatter(const int* __restrict__ src, const int* __restrict__ dst,
                          const int* __restrict__ offs, int* __restrict__ packed,
                          int E, int chunk, int K, int sbits) {
    extern __shared__ int cur[];
    int s = blockIdx.x;
    const int* orow = offs + (size_t)s * K;
    for (int i = threadIdx.x; i < K; i += BLK) cur[i] = orow[i];
    __syncthreads();
    int lo = s * chunk, hi = min(E, lo + chunk);
    for (int i = lo + threadIdx.x; i < hi; i += BLK) {
        int d = dst[i];
        int pos = atomicAdd(&cur[d >> BSHIFT], 1);
        packed[pos] = ((d & (BSIZE - 1)) << sbits) | src[i];
    }
}

// ---------------- aggregation passes (grid = K*M, private LDS tiles) -------

// degree counts -> degpart[b][BSIZE]
__global__ void k_deg(const int* __restrict__ packed, const int* __restrict__ base,
                      int M, int* __restrict__ degpart, int sbits) {
    __shared__ int cnt[BSIZE];
    int b = blockIdx.x;
    int k = b / M, m = b - k * M;
    for (int i = threadIdx.x; i < BSIZE; i += BLK) cnt[i] = 0;
    __syncthreads();
    int lo = base[k], len = base[k + 1] - lo;
    int l0 = lo + (int)(((long long)len * m) / M);
    int l1 = lo + (int)(((long long)len * (m + 1)) / M);
    for (int i = l0 + threadIdx.x; i < l1; i += BLK)
        atomicAdd(&cnt[((unsigned)packed[i]) >> sbits], 1);
    __syncthreads();
    int* outp = degpart + (size_t)b * BSIZE;
    for (int i = threadIdx.x; i < BSIZE; i += BLK) outp[i] = cnt[i];
}

// sum p[src] into private LDS tile -> partial[b][BSIZE][2]
__global__ void k_agg(const int* __restrict__ packed, const int* __restrict__ base,
                      int M, const float2* __restrict__ pin, float* __restrict__ partial,
                      int sbits, int smask) {
    __shared__ float acc[BSIZE * 2];
    int b = blockIdx.x;
    int k = b / M, m = b - k * M;
    for (int i = threadIdx.x; i < BSIZE * 2; i += BLK) acc[i] = 0.f;
    __syncthreads();
    int lo = base[k], len = base[k + 1] - lo;
    int l0 = lo + (int)(((long long)len * m) / M);
    int l1 = lo + (int)(((long long)len * (m + 1)) / M);
    for (int i = l0 + threadIdx.x; i < l1; i += BLK) {
        unsigned v = (unsigned)packed[i];
        int l = v >> sbits;
        float2 pv = pin[v & smask];
        atomicAdd(&acc[2 * l], pv.x);
        atomicAdd(&acc[2 * l + 1], pv.y);
    }
    __syncthreads();
    float* outp = partial + (size_t)b * (BSIZE * 2);
    for (int i = threadIdx.x * 4; i < BSIZE * 2; i += BLK * 4)
        *(float4*)(outp + i) = *(const float4*)(acc + i);
}

// ---------------- node epilogues ----------------

__global__ void k_node1(const int* __restrict__ degpart, int M,
                        const float* __restrict__ x, const float* __restrict__ W1,
                        float* __restrict__ dinv, float2* __restrict__ p1, int N) {
    int i = blockIdx.x * BLK + threadIdx.x;
    if (i >= N) return;
    int k = i >> BSHIFT, l = i & (BSIZE - 1);
    int c = 0;
    for (int m = 0; m < M; ++m) c += degpart[((size_t)(k * M + m)) * BSIZE + l];
    float di = rsqrtf((float)c + 1.0f);
    dinv[i] = di;
    float2 xv = ((const float2*)x)[i];
    float w00 = W1[0], w01 = W1[1], w10 = W1[2], w11 = W1[3];
    p1[i] = make_float2(di * (xv.x * w00 + xv.y * w10),
                        di * (xv.x * w01 + xv.y * w11));
}

__global__ void k_node_mid(const float* __restrict__ partial, int M,
                           const float* __restrict__ dinv, const float2* __restrict__ pin,
                           const float* __restrict__ b, const float* __restrict__ W,
                           float2* __restrict__ pout, int N) {
    int i = blockIdx.x * BLK + threadIdx.x;
    if (i >= N) return;
    int k = i >> BSHIFT, l = i & (BSIZE - 1);
    float2 self = pin[i];
    float ax = self.x, ay = self.y;
    for (int m = 0; m < M; ++m) {
        const float* pp = partial + ((size_t)(k * M + m)) * (BSIZE * 2) + 2 * l;
        ax += pp[0]; ay += pp[1];
    }
    float di = dinv[i];
    float h0 = fmaxf(fmaf(di, ax, b[0]), 0.f);
    float h1 = fmaxf(fmaf(di, ay, b[1]), 0.f);
    float w00 = W[0], w01 = W[1], w10 = W[2], w11 = W[3];
    pout[i] = make_float2(di * (h0 * w00 + h1 * w10),
                          di * (h0 * w01 + h1 * w11));
}

__global__ void k_out_init(float* __restrict__ out, const float* __restrict__ br, int G) {
    int i = blockIdx.x * BLK + threadIdx.x;
    if (i < G) out[i] = br[0];
}

// final layer epilogue fused with global_add_pool (sorted batch keys)
__global__ void k_node_final(const float* __restrict__ partial, int M,
                             const float* __restrict__ dinv, const float2* __restrict__ pin,
                             const float* __restrict__ b, const float* __restrict__ Wr,
                             const int* __restrict__ batch, float* __restrict__ out, int N) {
    int i = blockIdx.x * BLK + threadIdx.x;
    bool valid = i < N;
    float s = 0.f;
    int key = -1;
    if (valid) {
        int k = i >> BSHIFT, l = i & (BSIZE - 1);
        float2 self = pin[i];
        float ax = self.x, ay = self.y;
        for (int m = 0; m < M; ++m) {
            const float* pp = partial + ((size_t)(k * M + m)) * (BSIZE * 2) + 2 * l;
            ax += pp[0]; ay += pp[1];
        }
        float di = dinv[i];
        float h0 = fmaxf(fmaf(di, ax, b[0]), 0.f);
        float h1 = fmaxf(fmaf(di, ay, b[1]), 0.f);
        s = fmaf(h0, Wr[0], h1 * Wr[1]);
        key = batch[i];
    }
    int lane = threadIdx.x & 63;
    for (int off = 1; off < 64; off <<= 1) {
        float s2 = __shfl_down(s, off);
        int k2 = __shfl_down(key, off);
        if (lane + off < 64 && k2 == key) s += s2;
    }
    int kprev = __shfl_up(key, 1);
    if (valid && (lane == 0 || kprev != key)) unsafeAtomicAdd(&out[key], s);
}

// ---------------- launch ----------------

extern "C" void kernel_launch(void* const* d_in, const int* in_sizes, int n_in,
                              void* d_out, int out_size, void* d_ws, size_t ws_size,
                              hipStream_t stream) {
    const float* x    = (const float*)d_in[0];
    const int*   ei   = (const int*)d_in[1];
    const int*   batch= (const int*)d_in[2];
    const float* W1   = (const float*)d_in[3];
    const float* b1   = (const float*)d_in[4];
    const float* W2   = (const float*)d_in[5];
    const float* b2   = (const float*)d_in[6];
    const float* W3   = (const float*)d_in[7];
    const float* b3   = (const float*)d_in[8];
    const float* Wr   = (const float*)d_in[9];
    const float* br   = (const float*)d_in[10];
    float* out = (float*)d_out;

    int N = in_sizes[0] / 2;
    int E = in_sizes[1] / 2;
    int G = out_size;
    const int* src = ei;
    const int* dst = ei + E;

    int K = (N + BSIZE - 1) >> BSHIFT;
    if (K > SCAN_T) return;                     // unsupported shape -> fail loud
    int S = NSLICE;
    int chunk = (E + S - 1) / S;

    int sbits = 1;
    while ((1 << sbits) < N) ++sbits;           // src bit width (18 for N=200000)
    if (sbits + BSHIFT > 32) return;
    int smask = (1 << sbits) - 1;

    // pick M (sub-blocks per bucket) to fit workspace
    int M = 4;
    size_t need;
    for (;;) {
        need = ((size_t)E * 4 + 15 & ~(size_t)15)
             + (((size_t)S * K * 4 + 15) & ~(size_t)15)
             + (((size_t)(K + 1) * 4 + 15) & ~(size_t)15)
             + (((size_t)K * 4 + 15) & ~(size_t)15)
             + (((size_t)K * M * BSIZE * 2 * 4 + 15) & ~(size_t)15)
             + (((size_t)N * 4 + 15) & ~(size_t)15)
             + 2 * (((size_t)N * 8 + 15) & ~(size_t)15);
        if (need <= ws_size || M == 1) break;
        M >>= 1;
    }
    if (need > ws_size) return;

    char* w = (char*)d_ws;
    size_t off = 0;
    auto carve = [&](size_t bytes) { void* p = w + off; off += (bytes + 15) & ~(size_t)15; return p; };
    int*    packed  = (int*)carve((size_t)E * 4);
    int*    hpart   = (int*)carve((size_t)S * K * 4);
    int*    basep   = (int*)carve((size_t)(K + 1) * 4);
    int*    totals  = (int*)carve((size_t)K * 4);
    float*  aggpart = (float*)carve((size_t)K * M * BSIZE * 2 * 4);
    float*  dinv    = (float*)carve((size_t)N * 4);
    float2* pA      = (float2*)carve((size_t)N * 8);
    float2* pB      = (float2*)carve((size_t)N * 8);
    int*    degpart = (int*)aggpart;            // reuse: consumed before first k_agg

    int KB = (K + BLK - 1) / BLK;
    int NB = (N + BLK - 1) / BLK;
    int GB = (G + BLK - 1) / BLK;
    size_t smemK = (size_t)K * 4;
    int KM = K * M;

    // build bucketed edge list
    k_hist   <<<S, BLK, smemK, stream>>>(dst, hpart, E, chunk, K);
    k_totals <<<KB, BLK, 0, stream>>>(hpart, totals, S, K);
    k_base   <<<1, SCAN_T, 0, stream>>>(totals, basep, K);
    k_offsets<<<K, NSLICE, 0, stream>>>(hpart, basep, K);
    k_scatter<<<S, BLK, smemK, stream>>>(src, dst, hpart, packed, E, chunk, K, sbits);

    // degree -> dinv, p1
    k_deg   <<<KM, BLK, 0, stream>>>(packed, basep, M, degpart, sbits);
    k_node1 <<<NB, BLK, 0, stream>>>(degpart, M, x, W1, dinv, pA, N);

    // layer 1
    k_agg     <<<KM, BLK, 0, stream>>>(packed, basep, M, pA, aggpart, sbits, smask);
    k_node_mid<<<NB, BLK, 0, stream>>>(aggpart, M, dinv, pA, b1, W2, pB, N);
    // layer 2
    k_agg     <<<KM, BLK, 0, stream>>>(packed, basep, M, pB, aggpart, sbits, smask);
    k_node_mid<<<NB, BLK, 0, stream>>>(aggpart, M, dinv, pB, b2, W3, pA, N);
    // layer 3 + pool
    k_agg     <<<KM, BLK, 0, stream>>>(packed, basep, M, pA, aggpart, sbits, smask);
    k_out_init<<<GB, BLK, 0, stream>>>(out, br, G);
    k_node_final<<<NB, BLK, 0, stream>>>(aggpart, M, dinv, pA, b3, Wr, batch, out, N);
}